// Round 7
// baseline (627.942 us; speedup 1.0000x reference)
//
#include <hip/hip_runtime.h>
#include <math.h>

// Shapes: B=8, C=256, H=W=64, HQ=WQ=32, L=1024, NH=8, hd=8, dv=32
// Workspace layout: see offsets in kernel_launch (unchanged from R6).

typedef __attribute__((ext_vector_type(8))) short bf16x8;
typedef __attribute__((ext_vector_type(4))) float f32x4;

__device__ __forceinline__ ushort f2bf(float f) {
  union { float f; unsigned u; } v; v.f = f;
  unsigned r = (v.u + 0x7FFFu + ((v.u >> 16) & 1u)) >> 16;
  return (ushort)r;
}

#define GLDS(src, dst) __builtin_amdgcn_global_load_lds( \
    (const __attribute__((address_space(1))) unsigned*)(src), \
    (__attribute__((address_space(3))) unsigned*)(dst), 16, 0, 0)

// -------- weight pre-pack: W[oc][cin][3][3] fp32 -> [t][oc][cin] bf16 -------
template <int CIN>
__global__ __launch_bounds__(256) void k_prepack9(
    const float* __restrict__ W, ushort* __restrict__ out)
{
  const int i = blockIdx.x * 256 + threadIdx.x;
  const int t = i / (256 * CIN);
  const int r = i - t * (256 * CIN);
  const int oc = r / CIN;
  const int c = r - oc * CIN;
  out[i] = f2bf(W[((size_t)oc * CIN + c) * 9 + t]);
}

// -------- concat Wq/Wk/Wv -> bf16 [384][1024] -------------------------------
__global__ __launch_bounds__(256) void k_cast_wqkv(
    const float* __restrict__ Wq, const float* __restrict__ Wk,
    const float* __restrict__ Wv, ushort* __restrict__ out)
{
  const int i = blockIdx.x * 256 + threadIdx.x;
  const int o = i >> 10, k = i & 1023;
  float v;
  if (o < 64)       v = Wq[(size_t)o * 1024 + k];
  else if (o < 128) v = Wk[(size_t)(o - 64) * 1024 + k];
  else              v = Wv[(size_t)(o - 128) * 1024 + k];
  out[i] = f2bf(v);
}

// -------- patchify x (2x2 stride-2 im2col) -> bf16 Ap[b][l][1024] -----------
__global__ __launch_bounds__(256) void k_pack_pos(
    const float* __restrict__ x, ushort* __restrict__ Ap)
{
  const int t = blockIdx.x * 256 + threadIdx.x;
  const int j4 = t & 7;
  const int i  = (t >> 3) & 31;
  const int c  = (t >> 8) & 255;
  const int b  = t >> 16;
  const float* xb = x + (((size_t)b * 256 + c) << 12) + (2 * i) * 64 + 8 * j4;
  union { float4 v[2]; float f[8]; } r0, r1;
  r0.v[0] = *(const float4*)(xb);
  r0.v[1] = *(const float4*)(xb + 4);
  r1.v[0] = *(const float4*)(xb + 64);
  r1.v[1] = *(const float4*)(xb + 68);
  #pragma unroll
  for (int jj = 0; jj < 4; ++jj) {
    const int l = i * 32 + j4 * 4 + jj;
    union { ushort u[4]; uint2 d; } pk;
    pk.u[0] = f2bf(r0.f[2 * jj]);
    pk.u[1] = f2bf(r0.f[2 * jj + 1]);
    pk.u[2] = f2bf(r1.f[2 * jj]);
    pk.u[3] = f2bf(r1.f[2 * jj + 1]);
    *(uint2*)(Ap + ((((size_t)b << 10) + l) << 10) + c * 4) = pk.d;
  }
}

// ---- P1: POS q/k/v projection as bf16 MFMA GEMM, double-buffered -----------
__global__ __launch_bounds__(256) void k_pos_qkv_mfma(
    const ushort* __restrict__ Ap, const ushort* __restrict__ Wqkv,
    const float* __restrict__ bq, const float* __restrict__ bk,
    const float* __restrict__ bv,
    ushort* __restrict__ Qb, ushort* __restrict__ Kb, ushort* __restrict__ Vtb)
{
  const int flat = blockIdx.x;           // 192 = 24 tiles x 8 b
  const int b = flat & 7;
  const int t2 = flat >> 3;
  const int n0 = (t2 & 7) * 128, oc0 = (t2 >> 3) * 128;
  const int tid = threadIdx.x, lane = tid & 63, w = tid >> 6;
  __shared__ ushort As[2][128][32], Bs[2][128][32];
  const ushort* Abw = Wqkv + (size_t)oc0 * 1024;
  const ushort* Bb  = Ap + (((size_t)b << 10) + n0) * 1024;
  const int wr = w >> 1, wc = w & 1;
  const int rowq = (w * 128 + lane) >> 2 << 0;  // idx>>2 for q computed below
  f32x4 acc[4][4];
  #pragma unroll
  for (int mi = 0; mi < 4; ++mi)
    #pragma unroll
    for (int ni = 0; ni < 4; ++ni) {
      f32x4 z = {0.f, 0.f, 0.f, 0.f};
      acc[mi][ni] = z;
    }
  int rq[2], sq[2];
  #pragma unroll
  for (int q = 0; q < 2; ++q) {
    int idx = w * 128 + q * 64 + lane;
    rq[q] = idx >> 2;
    sq[q] = (idx & 3) * 8;
  }
  auto issue = [&](int buf, int kc) {
    #pragma unroll
    for (int q = 0; q < 2; ++q) {
      GLDS(Abw + (size_t)rq[q] * 1024 + kc + sq[q],
           (char*)&As[buf][0][0] + w * 2048 + q * 1024);
      GLDS(Bb + (size_t)rq[q] * 1024 + kc + sq[q],
           (char*)&Bs[buf][0][0] + w * 2048 + q * 1024);
    }
  };
  issue(0, 0);
  for (int ck = 0; ck < 32; ++ck) {
    const int buf = ck & 1;
    __syncthreads();
    if (ck + 1 < 32) issue(buf ^ 1, (ck + 1) * 32);
    bf16x8 af[4], bfv[4];
    #pragma unroll
    for (int mi = 0; mi < 4; ++mi)
      af[mi] = *(const bf16x8*)&As[buf][wr * 64 + mi * 16 + (lane & 15)][(lane >> 4) * 8];
    #pragma unroll
    for (int ni = 0; ni < 4; ++ni)
      bfv[ni] = *(const bf16x8*)&Bs[buf][wc * 64 + ni * 16 + (lane & 15)][(lane >> 4) * 8];
    #pragma unroll
    for (int mi = 0; mi < 4; ++mi)
      #pragma unroll
      for (int ni = 0; ni < 4; ++ni)
        acc[mi][ni] = __builtin_amdgcn_mfma_f32_16x16x32_bf16(
            af[mi], bfv[ni], acc[mi][ni], 0, 0, 0);
  }
  (void)rowq;
  // epilogue: scatter into flash layouts (Q scaled, bias added)
  #pragma unroll
  for (int mi = 0; mi < 4; ++mi) {
    const int oc = oc0 + wr * 64 + mi * 16 + (lane >> 4) * 4;
    if (oc >= 384) continue;
    if (oc < 64) {
      const int hh = oc >> 3, e = oc & 7;
      float4 bb = *(const float4*)(bq + oc);
      #pragma unroll
      for (int ni = 0; ni < 4; ++ni) {
        const int l = n0 + wc * 64 + ni * 16 + (lane & 15);
        union { ushort u[4]; uint2 d; } pk;
        pk.u[0] = f2bf((acc[mi][ni][0] + bb.x) * 0.35355339059327373f);
        pk.u[1] = f2bf((acc[mi][ni][1] + bb.y) * 0.35355339059327373f);
        pk.u[2] = f2bf((acc[mi][ni][2] + bb.z) * 0.35355339059327373f);
        pk.u[3] = f2bf((acc[mi][ni][3] + bb.w) * 0.35355339059327373f);
        *(uint2*)(Qb + (((((size_t)b * 8 + hh) << 10) + l) << 5) + e) = pk.d;
      }
    } else if (oc < 128) {
      const int o2 = oc - 64, hh = o2 >> 3, e = o2 & 7;
      float4 bb = *(const float4*)(bk + o2);
      #pragma unroll
      for (int ni = 0; ni < 4; ++ni) {
        const int l = n0 + wc * 64 + ni * 16 + (lane & 15);
        union { ushort u[4]; uint2 d; } pk;
        pk.u[0] = f2bf(acc[mi][ni][0] + bb.x);
        pk.u[1] = f2bf(acc[mi][ni][1] + bb.y);
        pk.u[2] = f2bf(acc[mi][ni][2] + bb.z);
        pk.u[3] = f2bf(acc[mi][ni][3] + bb.w);
        *(uint2*)(Kb + (((((size_t)b * 8 + hh) << 10) + l) << 5) + e) = pk.d;
      }
    } else {
      const int o2 = oc - 128, hh = o2 >> 5, dd = o2 & 31;
      float4 bb = *(const float4*)(bv + o2);
      #pragma unroll
      for (int ni = 0; ni < 4; ++ni) {
        const int l = n0 + wc * 64 + ni * 16 + (lane & 15);
        ushort* vb = Vtb + ((((size_t)b * 8 + hh) * 32 + dd) << 10) + l;
        vb[0]      = f2bf(acc[mi][ni][0] + bb.x);
        vb[1024]   = f2bf(acc[mi][ni][1] + bb.y);
        vb[2048]   = f2bf(acc[mi][ni][2] + bb.z);
        vb[3072]   = f2bf(acc[mi][ni][3] + bb.w);
      }
    }
  }
}

// ---- P2: flash POS attention, bf16 MFMA, no barriers -----------------------
__global__ __launch_bounds__(256) void k_pos_flash(
    const ushort* __restrict__ Qb, const ushort* __restrict__ Kb,
    const ushort* __restrict__ Vtb, ushort* __restrict__ op_pad)
{
  const int qt = blockIdx.x, h = blockIdx.y, b = blockIdx.z;
  const int bh = b * 8 + h;
  const int tid = threadIdx.x, lane = tid & 63, wq = tid >> 6;
  const int c = lane & 15, g = lane >> 4;
  __shared__ __align__(16) ushort Ps[4][32][72];
  const int qbase = qt * 128 + wq * 32;
  bf16x8 qf[2];
  #pragma unroll
  for (int nt = 0; nt < 2; ++nt)
    qf[nt] = *(const bf16x8*)(Qb + (((size_t)bh << 10) + qbase + nt * 16 + c) * 32 + g * 8);
  f32x4 o[2][2];
  #pragma unroll
  for (int mt = 0; mt < 2; ++mt)
    #pragma unroll
    for (int nt = 0; nt < 2; ++nt) {
      f32x4 z = {0.f, 0.f, 0.f, 0.f};
      o[mt][nt] = z;
    }
  float m[2] = {-1e30f, -1e30f}, l[2] = {0.f, 0.f};
  const ushort* Kbh = Kb + ((size_t)bh << 15);
  const ushort* Vbh = Vtb + ((size_t)bh << 15);

  for (int kt = 0; kt < 16; ++kt) {
    const int kb0 = kt * 64;
    bf16x8 kf[4];
    #pragma unroll
    for (int mt = 0; mt < 4; ++mt)
      kf[mt] = *(const bf16x8*)(Kbh + (size_t)(kb0 + mt * 16 + c) * 32 + g * 8);
    f32x4 s[4][2];
    #pragma unroll
    for (int mt = 0; mt < 4; ++mt)
      #pragma unroll
      for (int nt = 0; nt < 2; ++nt) {
        f32x4 z = {0.f, 0.f, 0.f, 0.f};
        s[mt][nt] = __builtin_amdgcn_mfma_f32_16x16x32_bf16(kf[mt], qf[nt], z, 0, 0, 0);
      }
    #pragma unroll
    for (int nt = 0; nt < 2; ++nt) {
      float tmax = -1e30f;
      #pragma unroll
      for (int mt = 0; mt < 4; ++mt)
        #pragma unroll
        for (int r = 0; r < 4; ++r)
          tmax = fmaxf(tmax, s[mt][nt][r]);
      tmax = fmaxf(tmax, __shfl_xor(tmax, 16, 64));
      tmax = fmaxf(tmax, __shfl_xor(tmax, 32, 64));
      const float mn = fmaxf(m[nt], tmax);
      const float alpha = __expf(m[nt] - mn);
      m[nt] = mn;
      float rs = 0.f;
      #pragma unroll
      for (int mt = 0; mt < 4; ++mt) {
        union { ushort u[4]; uint2 d; } pk;
        #pragma unroll
        for (int r = 0; r < 4; ++r) {
          float p = __expf(s[mt][nt][r] - mn);
          rs += p;
          pk.u[r] = f2bf(p);
        }
        *(uint2*)&Ps[wq][nt * 16 + c][mt * 16 + g * 4] = pk.d;
      }
      rs += __shfl_xor(rs, 16, 64);
      rs += __shfl_xor(rs, 32, 64);
      l[nt] = l[nt] * alpha + rs;
      #pragma unroll
      for (int mt = 0; mt < 2; ++mt)
        #pragma unroll
        for (int r = 0; r < 4; ++r)
          o[mt][nt][r] *= alpha;
    }
    #pragma unroll
    for (int kc = 0; kc < 2; ++kc) {
      bf16x8 vf[2], pf[2];
      #pragma unroll
      for (int mt = 0; mt < 2; ++mt)
        vf[mt] = *(const bf16x8*)(Vbh + (size_t)(mt * 16 + c) * 1024 + kb0 + kc * 32 + g * 8);
      #pragma unroll
      for (int nt = 0; nt < 2; ++nt)
        pf[nt] = *(const bf16x8*)&Ps[wq][nt * 16 + c][kc * 32 + g * 8];
      #pragma unroll
      for (int mt = 0; mt < 2; ++mt)
        #pragma unroll
        for (int nt = 0; nt < 2; ++nt)
          o[mt][nt] = __builtin_amdgcn_mfma_f32_16x16x32_bf16(vf[mt], pf[nt], o[mt][nt], 0, 0, 0);
    }
  }
  #pragma unroll
  for (int nt = 0; nt < 2; ++nt) {
    const float linv = 1.f / l[nt];
    const int q = qbase + nt * 16 + c;
    const int y = q >> 5, x = q & 31;
    ushort* dst = op_pad + ((size_t)b * 1156 + (y + 1) * 34 + (x + 1)) * 256 + h * 32;
    #pragma unroll
    for (int mt = 0; mt < 2; ++mt) {
      union { ushort u[4]; uint2 d; } pk;
      #pragma unroll
      for (int r = 0; r < 4; ++r)
        pk.u[r] = f2bf(o[mt][nt][r] * linv);
      *(uint2*)(dst + mt * 16 + g * 4) = pk.d;
    }
  }
}

// ------ 3x3 conv as 9 shifted GEMMs, double-buffered, XCD-affine grid -------
// grid: flat blocks = NT*OCT*8, b = blockIdx.x & 7 (XCD L2 affinity)
template <int CIN, int S, int PW, int OUT_NHWC>
__global__ __launch_bounds__(256) void k_conv9_mfma(
    const ushort* __restrict__ in, const ushort* __restrict__ W9,
    const float* __restrict__ bias, float* __restrict__ out)
{
  constexpr int NT = (S * S) / 128;
  constexpr int KCH = CIN / 32;
  constexpr int NCH = 9 * KCH;
  const int flat = blockIdx.x;
  const int b = flat & 7;
  const int t2 = flat >> 3;
  const int n0 = (t2 % NT) * 128;
  const int oc0 = (t2 / NT) * 128;
  const int tid = threadIdx.x, lane = tid & 63, w = tid >> 6;
  __shared__ ushort As[2][128][32], Bs[2][128][32];
  const int wr = w >> 1, wc = w & 1;
  f32x4 acc[4][4];
  #pragma unroll
  for (int mi = 0; mi < 4; ++mi)
    #pragma unroll
    for (int ni = 0; ni < 4; ++ni) {
      f32x4 z = {0.f, 0.f, 0.f, 0.f};
      acc[mi][ni] = z;
    }
  int rq[2], sq[2], basep[2];
  #pragma unroll
  for (int q = 0; q < 2; ++q) {
    int idx = w * 128 + q * 64 + lane;
    rq[q] = idx >> 2;
    sq[q] = (idx & 3) * 8;
    int n = n0 + rq[q];
    int y = n / S, x = n % S;
    basep[q] = y * PW + x;
  }
  const ushort* inb = in + (size_t)b * (PW * PW) * CIN;
  auto issue = [&](int buf, int ck) {
    const int t = ck / KCH;
    const int kc = (ck - t * KCH) * 32;
    const int offp = (t / 3) * PW + (t % 3);
    const ushort* wt = W9 + (size_t)t * 256 * CIN;
    #pragma unroll
    for (int q = 0; q < 2; ++q) {
      GLDS(wt + (size_t)(oc0 + rq[q]) * CIN + kc + sq[q],
           (char*)&As[buf][0][0] + w * 2048 + q * 1024);
      GLDS(inb + (size_t)(basep[q] + offp) * CIN + kc + sq[q],
           (char*)&Bs[buf][0][0] + w * 2048 + q * 1024);
    }
  };
  issue(0, 0);
  for (int ck = 0; ck < NCH; ++ck) {
    const int buf = ck & 1;
    __syncthreads();
    if (ck + 1 < NCH) issue(buf ^ 1, ck + 1);
    bf16x8 af[4], bfv[4];
    #pragma unroll
    for (int mi = 0; mi < 4; ++mi)
      af[mi] = *(const bf16x8*)&As[buf][wr * 64 + mi * 16 + (lane & 15)][(lane >> 4) * 8];
    #pragma unroll
    for (int ni = 0; ni < 4; ++ni)
      bfv[ni] = *(const bf16x8*)&Bs[buf][wc * 64 + ni * 16 + (lane & 15)][(lane >> 4) * 8];
    #pragma unroll
    for (int mi = 0; mi < 4; ++mi)
      #pragma unroll
      for (int ni = 0; ni < 4; ++ni)
        acc[mi][ni] = __builtin_amdgcn_mfma_f32_16x16x32_bf16(
            af[mi], bfv[ni], acc[mi][ni], 0, 0, 0);
  }
  if (OUT_NHWC) {
    float* outb = out + (size_t)b * (S * S) * 256;
    #pragma unroll
    for (int mi = 0; mi < 4; ++mi) {
      const int oc = oc0 + wr * 64 + mi * 16 + (lane >> 4) * 4;
      float4 bb = *(const float4*)(bias + oc);
      #pragma unroll
      for (int ni = 0; ni < 4; ++ni) {
        const int n = n0 + wc * 64 + ni * 16 + (lane & 15);
        float4 v;
        v.x = acc[mi][ni][0] + bb.x;
        v.y = acc[mi][ni][1] + bb.y;
        v.z = acc[mi][ni][2] + bb.z;
        v.w = acc[mi][ni][3] + bb.w;
        *(float4*)(outb + (size_t)n * 256 + oc) = v;
      }
    }
  } else {
    float* outb = out + (size_t)b * 256 * (S * S);
    #pragma unroll
    for (int mi = 0; mi < 4; ++mi) {
      #pragma unroll
      for (int r = 0; r < 4; ++r) {
        int oc = oc0 + wr * 64 + mi * 16 + (lane >> 4) * 4 + r;
        float bb = bias[oc];
        #pragma unroll
        for (int ni = 0; ni < 4; ++ni) {
          int n = n0 + wc * 64 + ni * 16 + (lane & 15);
          outb[(size_t)oc * (S * S) + n] = acc[mi][ni][r] + bb;
        }
      }
    }
  }
}

// ---- P4: bilinear x2 upsample + residual -> fused_pad[.., ch 0:256] --------
__global__ __launch_bounds__(256) void k_upsample_nhwc(
    const float* __restrict__ xpos, const float* __restrict__ opc,
    const float* __restrict__ gamma, ushort* __restrict__ fused)
{
  const int t = blockIdx.x * 256 + threadIdx.x;
  const int c = (t & 63) * 4;
  const int pix = (t >> 6) & 4095;
  const int b = t >> 18;
  const int y = pix >> 6, xx = pix & 63;
  const int my = y >> 1;
  const int y0 = (y & 1) ? my : my - 1;
  const float fy = (y & 1) ? 0.25f : 0.75f;
  const int mx = xx >> 1;
  const int x0 = (xx & 1) ? mx : mx - 1;
  const float fx = (xx & 1) ? 0.25f : 0.75f;
  const int y0c = max(y0, 0), y1c = min(y0 + 1, 31);
  const int x0c = max(x0, 0), x1c = min(x0 + 1, 31);
  const float* base = opc + (size_t)b * 1024 * 256 + c;
  float4 v00 = *(const float4*)(base + (size_t)(y0c * 32 + x0c) * 256);
  float4 v01 = *(const float4*)(base + (size_t)(y0c * 32 + x1c) * 256);
  float4 v10 = *(const float4*)(base + (size_t)(y1c * 32 + x0c) * 256);
  float4 v11 = *(const float4*)(base + (size_t)(y1c * 32 + x1c) * 256);
  const float w00 = (1.f - fy) * (1.f - fx), w01 = (1.f - fy) * fx;
  const float w10 = fy * (1.f - fx), w11 = fy * fx;
  const float g = gamma[0];
  const float* xr = xpos + ((size_t)b * 256 + c) * 4096 + pix;
  union { ushort u[4]; uint2 q; } o;
  o.u[0] = f2bf(xr[0]          + g * (w00 * v00.x + w01 * v01.x + w10 * v10.x + w11 * v11.x));
  o.u[1] = f2bf(xr[4096]       + g * (w00 * v00.y + w01 * v01.y + w10 * v10.y + w11 * v11.y));
  o.u[2] = f2bf(xr[2 * 4096]   + g * (w00 * v00.z + w01 * v01.z + w10 * v10.z + w11 * v11.z));
  o.u[3] = f2bf(xr[3 * 4096]   + g * (w00 * v00.w + w01 * v01.w + w10 * v10.w + w11 * v11.w));
  *(uint2*)(fused + ((size_t)b * 4356 + (y + 1) * 66 + (xx + 1)) * 512 + c) = o.q;
}

// ------- C0: CHA q/k/v grouped 2x2 projections -> bf16 (half-batch) ---------
__global__ __launch_bounds__(256) void k_cha_proj(
    const float* __restrict__ x,
    const float* __restrict__ Wq, const float* __restrict__ bq,
    const float* __restrict__ Wk, const float* __restrict__ bk,
    const float* __restrict__ Wv, const float* __restrict__ bv,
    ushort* __restrict__ Qc, ushort* __restrict__ Kc, ushort* __restrict__ Vt)
{
  const int t = blockIdx.x * 256 + threadIdx.x;
  const int bl = t >> 16;
  const int g  = (t >> 8) & 255;
  const int lq = t & 255;
  const int i = lq >> 3, j4 = (lq & 7) << 2;
  const float* xb = x + (((size_t)bl * 256 + g) << 12) + (2 * i) * 64 + 2 * j4;
  union { float4 v[2]; float f[8]; } xr0, xr1;
  xr0.v[0] = *(const float4*)(xb);
  xr0.v[1] = *(const float4*)(xb + 4);
  xr1.v[0] = *(const float4*)(xb + 64);
  xr1.v[1] = *(const float4*)(xb + 68);
  const int bhl = bl * 8 + (g >> 5);
  const int c2b = (g & 31) * 8;
  const int l0 = i * 32 + j4;
  #pragma unroll
  for (int h = 0; h < 8; ++h) {
    float4 w4 = *(const float4*)(Wq + g * 32 + h * 4);
    float bb = bq[g * 8 + h];
    union { ushort u[4]; uint2 q; } o;
    #pragma unroll
    for (int jj = 0; jj < 4; ++jj) {
      float v = xr0.f[2 * jj] * w4.x + xr0.f[2 * jj + 1] * w4.y
              + xr1.f[2 * jj] * w4.z + xr1.f[2 * jj + 1] * w4.w + bb;
      o.u[jj] = f2bf(v * 0.03125f);
    }
    *(uint2*)(Qc + (((size_t)bhl * 256 + c2b + h) << 10) + l0) = o.q;
  }
  #pragma unroll
  for (int h = 0; h < 8; ++h) {
    float4 w4 = *(const float4*)(Wk + g * 32 + h * 4);
    float bb = bk[g * 8 + h];
    union { ushort u[4]; uint2 q; } o;
    #pragma unroll
    for (int jj = 0; jj < 4; ++jj) {
      float v = xr0.f[2 * jj] * w4.x + xr0.f[2 * jj + 1] * w4.y
              + xr1.f[2 * jj] * w4.z + xr1.f[2 * jj + 1] * w4.w + bb;
      o.u[jj] = f2bf(v);
    }
    *(uint2*)(Kc + (((size_t)bhl * 256 + c2b + h) << 10) + l0) = o.q;
  }
  ushort vo[4][8];
  #pragma unroll
  for (int h = 0; h < 8; ++h) {
    float4 w4 = *(const float4*)(Wv + g * 32 + h * 4);
    float bb = bv[g * 8 + h];
    #pragma unroll
    for (int jj = 0; jj < 4; ++jj) {
      float v = xr0.f[2 * jj] * w4.x + xr0.f[2 * jj + 1] * w4.y
              + xr1.f[2 * jj] * w4.z + xr1.f[2 * jj + 1] * w4.w + bb;
      vo[jj][h] = f2bf(v);
    }
  }
  #pragma unroll
  for (int jj = 0; jj < 4; ++jj)
    *(uint4*)(Vt + ((size_t)bhl << 18) + (size_t)(l0 + jj) * 256 + c2b) =
        *(uint4*)&vo[jj][0];
}

// ------- C1: scores = qc @ kc^T, bf16 MFMA, K=1024, double-buffered ---------
__global__ __launch_bounds__(256) void k_cha_scores_mfma(
    const ushort* __restrict__ Qc, const ushort* __restrict__ Kc,
    float* __restrict__ S)
{
  const int c0 = blockIdx.x * 128, d0 = blockIdx.y * 128, bhl = blockIdx.z;
  const int tid = threadIdx.x, lane = tid & 63, w = tid >> 6;
  __shared__ ushort As[2][128][32], Bs[2][128][32];
  const ushort* Ab = Qc + ((size_t)bhl * 256 + c0) * 1024;
  const ushort* Bb = Kc + ((size_t)bhl * 256 + d0) * 1024;
  const int wr = w >> 1, wc = w & 1;
  f32x4 acc[4][4];
  #pragma unroll
  for (int mi = 0; mi < 4; ++mi)
    #pragma unroll
    for (int ni = 0; ni < 4; ++ni) {
      f32x4 z = {0.f, 0.f, 0.f, 0.f};
      acc[mi][ni] = z;
    }
  int rq[2], sq[2];
  #pragma unroll
  for (int q = 0; q < 2; ++q) {
    int idx = w * 128 + q * 64 + lane;
    rq[q] = idx >> 2;
    sq[q] = (idx & 3) * 8;
  }
  auto issue = [&](int buf, int kc) {
    #pragma unroll
    for (int q = 0; q < 2; ++q) {
      GLDS(Ab + (size_t)rq[q] * 1024 + kc + sq[q],
           (char*)&As[buf][0][0] + w * 2048 + q * 1024);
      GLDS(Bb + (size_t)rq[q] * 1024 + kc + sq[q],
           (char*)&Bs[buf][0][0] + w * 2048 + q * 1024);
    }
  };
  issue(0, 0);
  for (int ck = 0; ck < 32; ++ck) {
    const int buf = ck & 1;
    __syncthreads();
    if (ck + 1 < 32) issue(buf ^ 1, (ck + 1) * 32);
    bf16x8 af[4], bfv[4];
    #pragma unroll
    for (int mi = 0; mi < 4; ++mi)
      af[mi] = *(const bf16x8*)&As[buf][wr * 64 + mi * 16 + (lane & 15)][(lane >> 4) * 8];
    #pragma unroll
    for (int ni = 0; ni < 4; ++ni)
      bfv[ni] = *(const bf16x8*)&Bs[buf][wc * 64 + ni * 16 + (lane & 15)][(lane >> 4) * 8];
    #pragma unroll
    for (int mi = 0; mi < 4; ++mi)
      #pragma unroll
      for (int ni = 0; ni < 4; ++ni)
        acc[mi][ni] = __builtin_amdgcn_mfma_f32_16x16x32_bf16(
            af[mi], bfv[ni], acc[mi][ni], 0, 0, 0);
  }
  float* Sb = S + ((size_t)bhl << 16);
  #pragma unroll
  for (int mi = 0; mi < 4; ++mi)
    #pragma unroll
    for (int r = 0; r < 4; ++r) {
      int c = c0 + wr * 64 + mi * 16 + (lane >> 4) * 4 + r;
      #pragma unroll
      for (int ni = 0; ni < 4; ++ni) {
        int d = d0 + wc * 64 + ni * 16 + (lane & 15);
        Sb[(size_t)c * 256 + d] = acc[mi][ni][r];
      }
    }
}

// ------- C2: row softmax over 256 -> bf16 P ---------------------------------
__global__ __launch_bounds__(256) void k_softmax_p(
    const float* __restrict__ S, ushort* __restrict__ P)
{
  const int row = blockIdx.x * 4 + (threadIdx.x >> 6);
  const int lane = threadIdx.x & 63;
  const float* r = S + (size_t)row * 256;
  float4 v = *(const float4*)(r + lane * 4);
  float m = fmaxf(fmaxf(v.x, v.y), fmaxf(v.z, v.w));
  #pragma unroll
  for (int off = 32; off; off >>= 1) m = fmaxf(m, __shfl_xor(m, off, 64));
  v.x = __expf(v.x - m); v.y = __expf(v.y - m);
  v.z = __expf(v.z - m); v.w = __expf(v.w - m);
  float s = v.x + v.y + v.z + v.w;
  #pragma unroll
  for (int off = 32; off; off >>= 1) s += __shfl_xor(s, off, 64);
  const float inv = 1.f / s;
  union { ushort u[4]; uint2 q; } o;
  o.u[0] = f2bf(v.x * inv); o.u[1] = f2bf(v.y * inv);
  o.u[2] = f2bf(v.z * inv); o.u[3] = f2bf(v.w * inv);
  *(uint2*)(P + (size_t)row * 256 + lane * 4) = o.q;
}

// -- C3: oc = P @ vcT (MFMA, dbuf) + grouped ConvT + residual -> NHWC --------
__global__ __launch_bounds__(256) void k_cha_pv(
    const ushort* __restrict__ P, const ushort* __restrict__ Vt,
    const float* __restrict__ x,
    const float* __restrict__ Wt, const float* __restrict__ bt,
    const float* __restrict__ gamma, ushort* __restrict__ fused, int bbase)
{
  const int n0 = blockIdx.x * 128, c0 = blockIdx.y * 128, bhl = blockIdx.z;
  const int b = bbase + (bhl >> 3), h = bhl & 7;
  const int tid = threadIdx.x, lane = tid & 63, w = tid >> 6;
  __shared__ ushort As[2][128][32], Bs[2][128][32];
  __shared__ ushort Ot[512][16];
  __shared__ float wt_s[16][32];
  __shared__ float bt_s[16];
  const int gp_base = h * 32 + (c0 >> 3);
  {
    int e = tid;
    wt_s[e >> 5][e & 31] = Wt[(size_t)gp_base * 32 + e];
    e += 256;
    wt_s[e >> 5][e & 31] = Wt[(size_t)gp_base * 32 + e];
    if (tid < 16) bt_s[tid] = bt[gp_base + tid];
  }
  const ushort* Ab = P + (((size_t)bhl << 8) + c0) * 256;
  const ushort* Bb = Vt + ((size_t)bhl << 18) + (size_t)n0 * 256;
  const int wr = w >> 1, wc = w & 1;
  f32x4 acc[4][4];
  #pragma unroll
  for (int mi = 0; mi < 4; ++mi)
    #pragma unroll
    for (int ni = 0; ni < 4; ++ni) {
      f32x4 z = {0.f, 0.f, 0.f, 0.f};
      acc[mi][ni] = z;
    }
  int rq[2], sq[2];
  #pragma unroll
  for (int q = 0; q < 2; ++q) {
    int idx = w * 128 + q * 64 + lane;
    rq[q] = idx >> 2;
    sq[q] = (idx & 3) * 8;
  }
  auto issue = [&](int buf, int kc) {
    #pragma unroll
    for (int q = 0; q < 2; ++q) {
      GLDS(Ab + (size_t)rq[q] * 256 + kc + sq[q],
           (char*)&As[buf][0][0] + w * 2048 + q * 1024);
      GLDS(Bb + (size_t)rq[q] * 256 + kc + sq[q],
           (char*)&Bs[buf][0][0] + w * 2048 + q * 1024);
    }
  };
  issue(0, 0);
  for (int ck = 0; ck < 8; ++ck) {
    const int buf = ck & 1;
    __syncthreads();
    if (ck + 1 < 8) issue(buf ^ 1, (ck + 1) * 32);
    bf16x8 af[4], bfv[4];
    #pragma unroll
    for (int mi = 0; mi < 4; ++mi)
      af[mi] = *(const bf16x8*)&As[buf][wr * 64 + mi * 16 + (lane & 15)][(lane >> 4) * 8];
    #pragma unroll
    for (int ni = 0; ni < 4; ++ni)
      bfv[ni] = *(const bf16x8*)&Bs[buf][wc * 64 + ni * 16 + (lane & 15)][(lane >> 4) * 8];
    #pragma unroll
    for (int mi = 0; mi < 4; ++mi)
      #pragma unroll
      for (int ni = 0; ni < 4; ++ni)
        acc[mi][ni] = __builtin_amdgcn_mfma_f32_16x16x32_bf16(
            af[mi], bfv[ni], acc[mi][ni], 0, 0, 0);
  }
  const float gm = gamma[0];
  const int col = lane & 15, q = lane >> 4;
  #pragma unroll
  for (int mi = 0; mi < 4; ++mi) {
    const int gloc = wr * 8 + mi * 2 + (q >> 1);
    const int gp = gp_base + gloc;
    const float btv = bt_s[gloc];
    #pragma unroll
    for (int ni = 0; ni < 4; ++ni) {
      float pa[4] = {0.f, 0.f, 0.f, 0.f};
      #pragma unroll
      for (int r = 0; r < 4; ++r) {
        const int i2 = (q & 1) * 4 + r;
        const float a = acc[mi][ni][r];
        pa[0] += a * wt_s[gloc][i2 * 4 + 0];
        pa[1] += a * wt_s[gloc][i2 * 4 + 1];
        pa[2] += a * wt_s[gloc][i2 * 4 + 2];
        pa[3] += a * wt_s[gloc][i2 * 4 + 3];
      }
      float v0 = pa[0] + __shfl_xor(pa[0], 16, 64);
      float v1 = pa[1] + __shfl_xor(pa[1], 16, 64);
      float v2 = pa[2] + __shfl_xor(pa[2], 16, 64);
      float v3 = pa[3] + __shfl_xor(pa[3], 16, 64);
      const int lloc = wc * 64 + ni * 16 + col;
      const int l = n0 + lloc;
      const int p = l >> 5, j = l & 31;
      const int y = 2 * p + (q & 1);
      const float va = (q & 1) ? v2 : v0;
      const float vb = (q & 1) ? v3 : v1;
      const float* xc = x + (((size_t)b * 256 + gp) << 12) + (y << 6) + 2 * j;
      const int lp = (lloc << 2) + (q & 1) * 2;
      Ot[lp][gloc]     = f2bf(xc[0] + gm * (va + btv));
      Ot[lp + 1][gloc] = f2bf(xc[1] + gm * (vb + btv));
    }
  }
  __syncthreads();
  #pragma unroll
  for (int pp2 = 0; pp2 < 2; ++pp2) {
    const int pixl = tid * 2 + pp2;
    const int lloc = pixl >> 2;
    const int l = n0 + lloc;
    const int p = l >> 5, j = l & 31;
    const int yy = 2 * p + ((pixl >> 1) & 1) + 1;
    const int xx = 2 * j + (pixl & 1) + 1;
    const uint4* src = (const uint4*)&Ot[pixl][0];
    uint4* dst = (uint4*)(fused + ((size_t)b * 4356 + yy * 66 + xx) * 512 + 256 + gp_base);
    dst[0] = src[0];
    dst[1] = src[1];
  }
}

extern "C" void kernel_launch(void* const* d_in, const int* in_sizes, int n_in,
                              void* d_out, int out_size, void* d_ws, size_t ws_size,
                              hipStream_t stream)
{
  (void)in_sizes; (void)n_in; (void)out_size; (void)ws_size;
  const float* qkv_pos   = (const float*)d_in[0];
  const float* qkv_cha   = (const float*)d_in[1];
  const float* Wq_pos    = (const float*)d_in[2];
  const float* bq_pos    = (const float*)d_in[3];
  const float* Wk_pos    = (const float*)d_in[4];
  const float* bk_pos    = (const float*)d_in[5];
  const float* Wv_pos    = (const float*)d_in[6];
  const float* bv_pos    = (const float*)d_in[7];
  const float* Wo_pos    = (const float*)d_in[8];
  const float* bo_pos    = (const float*)d_in[9];
  const float* gamma_pos = (const float*)d_in[10];
  const float* Wq_cha    = (const float*)d_in[11];
  const float* bq_cha    = (const float*)d_in[12];
  const float* Wk_cha    = (const float*)d_in[13];
  const float* bk_cha    = (const float*)d_in[14];
  const float* Wv_cha    = (const float*)d_in[15];
  const float* bv_cha    = (const float*)d_in[16];
  const float* Wt_cha    = (const float*)d_in[17];
  const float* bt_cha    = (const float*)d_in[18];
  const float* gamma_cha = (const float*)d_in[19];
  const float* Wf        = (const float*)d_in[20];
  const float* bf        = (const float*)d_in[21];
  float* out = (float*)d_out;

  float* ws = (float*)d_ws;
  ushort* Wpf9    = (ushort*)ws;
  ushort* Wpo9    = (ushort*)(ws + 589824);
  // POS scratch
  ushort* Qb      = (ushort*)(ws + 884736);    // [64][1024][32] bf16
  ushort* Kb      = (ushort*)(ws + 1933312);   // [64][1024][32] bf16
  ushort* Vtb     = (ushort*)(ws + 2981888);   // [64][32][1024] bf16
  ushort* op_pad  = (ushort*)(ws + 4030464);   // 2367488 ushorts
  float*  op_conv = ws + 5214208;              // NHWC fp32 [8][1024][256]
  ushort* Ap      = (ushort*)(ws + 7311360);   // [8][1024][1024] bf16
  // CHA scratch (aliases POS region after it is consumed)
  ushort* qcb     = (ushort*)(ws + 884736);
  ushort* kcb     = (ushort*)(ws + 5079040);
  ushort* vcT     = (ushort*)(ws + 9273344);
  float*  attn_c  = ws + 13467648;
  ushort* Pb      = (ushort*)(ws + 15564800);
  ushort* fusedb  = (ushort*)(ws + 16613376);  // NHWC padded [8][66*66][512]
  ushort* Wqkvp   = (ushort*)(ws + 25534464);  // [384][1024] bf16

  hipMemsetAsync(op_pad, 0, (size_t)2367488 * 2, stream);
  hipMemsetAsync(fusedb, 0, (size_t)17842176 * 2, stream);
  hipMemsetAsync(Qb, 0, (size_t)2097152 * 2, stream);
  k_prepack9<512><<<dim3(4608), 256, 0, stream>>>(Wf, Wpf9);
  k_prepack9<256><<<dim3(2304), 256, 0, stream>>>(Wo_pos, Wpo9);
  k_cast_wqkv<<<dim3(1536), 256, 0, stream>>>(Wq_pos, Wk_pos, Wv_pos, Wqkvp);
  // POS branch
  k_pack_pos<<<dim3(2048), 256, 0, stream>>>(qkv_pos, Ap);
  k_pos_qkv_mfma<<<dim3(192), 256, 0, stream>>>(Ap, Wqkvp,
      bq_pos, bk_pos, bv_pos, Qb, Kb, Vtb);
  k_pos_flash<<<dim3(8, 8, 8), 256, 0, stream>>>(Qb, Kb, Vtb, op_pad);
  k_conv9_mfma<256, 32, 34, 1><<<dim3(128), 256, 0, stream>>>(
      op_pad, Wpo9, bo_pos, op_conv);
  k_upsample_nhwc<<<dim3(8192), 256, 0, stream>>>(qkv_pos, op_conv, gamma_pos, fusedb);
  // CHA branch, two half-batches
  for (int half = 0; half < 2; ++half) {
    const float* xh = qkv_cha + (size_t)half * 4 * 256 * 4096;
    k_cha_proj<<<dim3(1024), 256, 0, stream>>>(xh, Wq_cha, bq_cha,
        Wk_cha, bk_cha, Wv_cha, bv_cha, qcb, kcb, vcT);
    k_cha_scores_mfma<<<dim3(2, 2, 32), 256, 0, stream>>>(qcb, kcb, attn_c);
    k_softmax_p<<<dim3(2048), 256, 0, stream>>>(attn_c, Pb);
    k_cha_pv<<<dim3(8, 2, 32), 256, 0, stream>>>(Pb, vcT, qkv_cha,
        Wt_cha, bt_cha, gamma_cha, fusedb, half * 4);
  }
  // fusion conv (bf16 MFMA over padded NHWC, XCD-affine flat grid)
  k_conv9_mfma<512, 64, 66, 0><<<dim3(512), 256, 0, stream>>>(
      fusedb, Wpf9, bf, out);
}